// Round 11
// baseline (355.462 us; speedup 1.0000x reference)
//
#include <hip/hip_runtime.h>
#include <hip/hip_bf16.h>
#include <stdint.h>

#define D 128
#define K 8
#define BGRAPH 64
#define CH 64    // edges per wave in gine_reduce
#define GRP 4    // edges per inner group

typedef __attribute__((ext_vector_type(8))) short bf16x8;
typedef __attribute__((ext_vector_type(4))) float f32x4;
typedef __attribute__((ext_vector_type(2))) float f32x2;

__device__ __forceinline__ short f2bf(float f) {
    union { float f; uint32_t u; } v; v.f = f;
    const uint32_t r = (v.u + 0x7fffu + ((v.u >> 16) & 1u)) >> 16;
    return (short)r;
}
__device__ __forceinline__ float bflo(uint32_t u) {
    union { uint32_t u; float f; } v; v.u = u << 16; return v.f;
}
__device__ __forceinline__ float bfhi(uint32_t u) {
    union { uint32_t u; float f; } v; v.u = u & 0xffff0000u; return v.f;
}

// ---------------------------------------------------------------------------
// Stage 0 (fused prep): cast x->bf16, W1/W2->bf16 transposed, We^T hi/lo bf16
// (K padded to 32, bias row at k=16), dst in-degree hist.
// ---------------------------------------------------------------------------
__global__ __launch_bounds__(256) void prep_kernel(
    const float* __restrict__ x,
    const float* __restrict__ W1, const float* __restrict__ W2,
    const float* __restrict__ We, const float* __restrict__ be,
    const int* __restrict__ dst,
    __hip_bfloat16* __restrict__ xb,
    short* __restrict__ wb1t, short* __restrict__ wb2t,
    short* __restrict__ webt,
    int* __restrict__ deg,
    int NX, int E, int NBX, int NBW)
{
    const int b = blockIdx.x;
    const int t = threadIdx.x;
    if (b < NBX) {
        // ---- cast x (8 floats/thread) ----
        const int i = b * 2048 + t * 8;
        if (i + 8 <= NX) {
            const float4 a = *(const float4*)(x + i);
            const float4 c = *(const float4*)(x + i + 4);
            short v[8];
            v[0] = f2bf(a.x); v[1] = f2bf(a.y); v[2] = f2bf(a.z); v[3] = f2bf(a.w);
            v[4] = f2bf(c.x); v[5] = f2bf(c.y); v[6] = f2bf(c.z); v[7] = f2bf(c.w);
            *(uint4*)((short*)xb + i) = *(const uint4*)v;
        }
    } else if (b < NBX + NBW) {
        const int idx = (b - NBX) * 256 + t;
        if (idx < 2 * D * D) {
            // ---- W1/W2 transpose cast (1 elem/thread) ----
            const int which = idx >> 14;           // 0: W1, 1: W2
            const int rem = idx & 16383;
            const int n = rem >> 7;
            const int k = rem & 127;
            const float* W = which ? W2 : W1;
            short* O = which ? wb2t : wb1t;
            O[n * D + k] = f2bf(W[(size_t)k * D + n]);
        } else {
            // ---- webt[2][128][32]: We^T hi/lo bf16, bias row at k=16 ----
            const int widx = idx - 2 * D * D;      // 0..8191
            const int h = widx >> 12;              // 0 hi, 1 lo
            const int c = (widx >> 5) & 127;
            const int k = widx & 31;
            float val = 0.f;
            if (k < 16) val = We[k * D + c];
            else if (k == 16) val = be[c];
            const short hi = f2bf(val);
            short outv;
            if (h == 0) outv = hi;
            else {
                union { uint32_t u; float f; } fh;
                fh.u = ((uint32_t)(unsigned short)hi) << 16;
                outv = f2bf(val - fh.f);
            }
            webt[(h << 12) + c * 32 + k] = outv;
        }
    } else {
        // ---- dst histogram (4 edges/thread) ----
        const int i = ((b - NBX - NBW) * 256 + t) * 4;
        if (i + 4 <= E) {
            const int4 v = *(const int4*)(dst + i);
            atomicAdd(&deg[v.x], 1);
            atomicAdd(&deg[v.y], 1);
            atomicAdd(&deg[v.z], 1);
            atomicAdd(&deg[v.w], 1);
        } else {
            for (int j = i; j < E; ++j) atomicAdd(&deg[dst[j]], 1);
        }
    }
}

// ---------------------------------------------------------------------------
// Stage 1b: two-phase exclusive scan of deg[N] -> cursor[N].
// scan_final folds in the old scan_top: every block redundantly scans the
// 49-entry bsum array in LDS (parallel across blocks; -1 dispatch).
// ---------------------------------------------------------------------------
__global__ __launch_bounds__(256) void scan_partial_kernel(
    const int* __restrict__ deg, int* __restrict__ bsum, int N)
{
    const int t = threadIdx.x;
    const int base = (blockIdx.x * 256 + t) * 4;
    int s = 0;
    if (base + 4 <= N) {
        const int4 v = *(const int4*)(deg + base);
        s = v.x + v.y + v.z + v.w;
    } else {
        for (int j = base; j < N; ++j) s += deg[j];
    }
    __shared__ int red[256];
    red[t] = s;
    __syncthreads();
    for (int off = 128; off; off >>= 1) {
        if (t < off) red[t] += red[t + off];
        __syncthreads();
    }
    if (t == 0) bsum[blockIdx.x] = red[0];
}

__global__ __launch_bounds__(256) void scan_final_kernel(
    const int* __restrict__ deg, const int* __restrict__ bsum,
    int* __restrict__ cursor, int N, int nb)
{
    __shared__ int topsh[64];
    __shared__ int sh[256];
    const int t = threadIdx.x;

    // ---- inline top-scan of bsum[nb] (nb <= 64) ----
    const int own = bsum[blockIdx.x];
    if (t < 64) topsh[t] = (t < nb) ? bsum[t] : 0;
    __syncthreads();
    for (int off = 1; off < 64; off <<= 1) {
        int u = 0;
        if (t < 64 && t >= off) u = topsh[t - off];
        __syncthreads();
        if (t < 64) topsh[t] += u;
        __syncthreads();
    }
    const int extop = topsh[blockIdx.x] - own;     // exclusive top offset

    const int base = (blockIdx.x * 256 + t) * 4;
    int v0 = 0, v1 = 0, v2 = 0, v3 = 0;
    if (base + 4 <= N) {
        const int4 v = *(const int4*)(deg + base);
        v0 = v.x; v1 = v.y; v2 = v.z; v3 = v.w;
    } else {
        if (base     < N) v0 = deg[base];
        if (base + 1 < N) v1 = deg[base + 1];
        if (base + 2 < N) v2 = deg[base + 2];
        if (base + 3 < N) v3 = deg[base + 3];
    }
    const int s = v0 + v1 + v2 + v3;
    sh[t] = s;
    __syncthreads();
    for (int off = 1; off < 256; off <<= 1) {
        const int u = (t >= off) ? sh[t - off] : 0;
        __syncthreads();
        sh[t] += u;
        __syncthreads();
    }
    int ex = extop + sh[t] - s;
    if (base < N)     { cursor[base]     = ex; } ex += v0;
    if (base + 1 < N) { cursor[base + 1] = ex; } ex += v1;
    if (base + 2 < N) { cursor[base + 2] = ex; } ex += v2;
    if (base + 3 < N) { cursor[base + 3] = ex; }
}

// ---------------------------------------------------------------------------
// Stage 1c: fused scatter (R5 form): packed (src|dst<<16, eid) into dst-
// grouped order AND bf16 ea row materialized at sorted position (coalesced
// ea read, scattered 32B write).
// ---------------------------------------------------------------------------
__global__ __launch_bounds__(256) void scatter_kernel(
    const int* __restrict__ src, const int* __restrict__ dst,
    const float* __restrict__ ea,
    int* __restrict__ cursor, uint2* __restrict__ md,
    short* __restrict__ eabs, int E)
{
    const int i = blockIdx.x * 256 + threadIdx.x;
    if (i < E) {
        const unsigned sv = (unsigned)src[i];
        const unsigned dv = (unsigned)dst[i];
        const int p = atomicAdd(&cursor[dv], 1);
        md[p] = make_uint2(sv | (dv << 16), (unsigned)i);
        const float4* ep = (const float4*)(ea + (size_t)i * 16);
        const float4 a = ep[0], b = ep[1], c = ep[2], e4 = ep[3];
        short v[16];
        v[0]  = f2bf(a.x);  v[1]  = f2bf(a.y);  v[2]  = f2bf(a.z);  v[3]  = f2bf(a.w);
        v[4]  = f2bf(b.x);  v[5]  = f2bf(b.y);  v[6]  = f2bf(b.z);  v[7]  = f2bf(b.w);
        v[8]  = f2bf(c.x);  v[9]  = f2bf(c.y);  v[10] = f2bf(c.z);  v[11] = f2bf(c.w);
        v[12] = f2bf(e4.x); v[13] = f2bf(e4.y); v[14] = f2bf(e4.z); v[15] = f2bf(e4.w);
        uint4* op = (uint4*)(eabs + (size_t)p * 16);
        op[0] = *(const uint4*)v;
        op[1] = *(const uint4*)(v + 8);
    }
}

// ---------------------------------------------------------------------------
// Stage 1d: edge-parallel gather-reduce. R10-exact EXCEPT the eemb LDS tile:
// 16x132 (33.8KB) -> 16x128 XOR-swizzled (32KB exactly) so blocks/CU rises
// 4 -> 5. Swizzle: write col ^ ((row>>2)&1)<<4, read col ^ same — banks stay
// 2-way (free) on both paths; values unchanged.
// ---------------------------------------------------------------------------
__device__ __forceinline__ void flush_row(
    float* __restrict__ agg, int node, int d, f32x2 acc, int first, int last)
{
    float* p = agg + (size_t)node * D + d;
    if (node == first || node == last) {
        if (acc.x != 0.f) atomicAdd(p,     acc.x);
        if (acc.y != 0.f) atomicAdd(p + 1, acc.y);
    } else {
        *(f32x2*)p = acc;
    }
}

__global__ __launch_bounds__(256) void gine_reduce_kernel(
    const __hip_bfloat16* __restrict__ xb, const uint2* __restrict__ md,
    const short* __restrict__ eabs, const short* __restrict__ webt,
    float* __restrict__ agg, int E)
{
    __shared__ float lsh[4][16 * 128];   // 32 KB total -> 5 blocks/CU
    const int wave = threadIdx.x >> 6;
    const int lane = threadIdx.x & 63;
    const int chunk = __builtin_amdgcn_readfirstlane(blockIdx.x * 4 + wave);
    const int e0 = chunk * CH;
    if (e0 >= E) return;
    const int d = lane * 2;
    const int m = lane & 15;
    const int q = lane >> 4;
    float* myl = lsh[wave];
    const int NG = CH / GRP;                       // 16
    const int qswz = (q & 1) << 4;                 // write-col xor (row>>2 & 1)

    // B fragments: col = ct*16+m, k = q*8..q*8+7 (hi and lo tables)
    bf16x8 bH[8], bL[8];
    #pragma unroll
    for (int ct = 0; ct < 8; ++ct) {
        bH[ct] = *(const bf16x8*)(webt +        (ct * 16 + m) * 32 + q * 8);
        bL[ct] = *(const bf16x8*)(webt + 4096 + (ct * 16 + m) * 32 + q * 8);
    }

    // A fragment for mgroup 0: STREAMING read at sorted position e0+m.
    uint4 afcur = *(const uint4*)(eabs + (size_t)(e0 + m) * 16 + (q & 1) * 8);

    // scalar md pipeline + x prefetch (GRP granularity)
    uint2 ma[GRP], mb[GRP], mc[GRP];
    #pragma unroll
    for (int j = 0; j < GRP; ++j) ma[j] = md[e0 + j];
    #pragma unroll
    for (int j = 0; j < GRP; ++j) mb[j] = md[e0 + GRP + j];
    #pragma unroll
    for (int j = 0; j < GRP; ++j) mc[j] = md[e0 + 2 * GRP + j];

    uint32_t xcur[GRP], xn1[GRP];
    #pragma unroll
    for (int j = 0; j < GRP; ++j)
        xcur[j] = *(const uint32_t*)(xb + (size_t)(ma[j].x & 0xffffu) * D + d);
    #pragma unroll
    for (int j = 0; j < GRP; ++j)
        xn1[j] = *(const uint32_t*)(xb + (size_t)(mb[j].x & 0xffffu) * D + d);

    const int first = (int)(ma[0].x >> 16);
    const int last  = (int)(md[e0 + CH - 1].x >> 16);

    f32x2 acc = {0.f, 0.f};
    int cur = first;

    for (int g = 0; g < NG; ++g) {
        if ((g & 3) == 0) {
            // ---- MFMA block for mgroup mg; streaming prefetch A for mg+1 ----
            const int mg = g >> 2;
            uint4 afn = make_uint4(0u, 0u, 0u, 0u);
            if (mg < 3)
                afn = *(const uint4*)(eabs +
                    (size_t)(e0 + (mg + 1) * 16 + m) * 16 + (q & 1) * 8);
            uint4 au = afcur;
            if (q >= 2)
                au = make_uint4(q == 2 ? 0x3f80u : 0u, 0u, 0u, 0u); // k16 = 1.0
            const bf16x8 a = *(const bf16x8*)&au;
            f32x4 mm[8];
            #pragma unroll
            for (int ct = 0; ct < 8; ++ct) {
                const f32x4 z = {0.f, 0.f, 0.f, 0.f};
                mm[ct] = __builtin_amdgcn_mfma_f32_16x16x32_bf16(a, bL[ct], z, 0, 0, 0);
            }
            #pragma unroll
            for (int ct = 0; ct < 8; ++ct)
                mm[ct] = __builtin_amdgcn_mfma_f32_16x16x32_bf16(a, bH[ct], mm[ct], 0, 0, 0);
            // C: edge row = q*4+r, col = (ct*16+m) ^ qswz  (2-way banks, free)
            #pragma unroll
            for (int ct = 0; ct < 8; ++ct)
                #pragma unroll
                for (int r = 0; r < 4; ++r)
                    myl[(q * 4 + r) * 128 + ((ct * 16 + m) ^ qswz)] = mm[ct][r];
            afcur = afn;
        }

        // prefetch: meta g+3, x g+2
        uint2 mnn[GRP] = {};
        uint32_t xn2[GRP] = {};
        if (g + 3 < NG) {
            #pragma unroll
            for (int j = 0; j < GRP; ++j) mnn[j] = md[e0 + (g + 3) * GRP + j];
        }
        if (g + 2 < NG) {
            #pragma unroll
            for (int j = 0; j < GRP; ++j)
                xn2[j] = *(const uint32_t*)(xb + (size_t)(mc[j].x & 0xffffu) * D + d);
        }

        #pragma unroll
        for (int j = 0; j < GRP; ++j) {
            const int dk = (int)(ma[j].x >> 16);
            if (dk != cur) {                  // wave-uniform scalar branch
                flush_row(agg, cur, d, acc, first, last);
                acc.x = 0.f; acc.y = 0.f;
                cur = dk;
            }
            const uint32_t xu = xcur[j];
            const int el = (g & 3) * GRP + j;
            const float2 em = *(const float2*)(myl + el * 128 +
                                               (d ^ ((el & 4) << 2)));
            const float v0 = em.x + bflo(xu);
            const float v1 = em.y + bfhi(xu);
            acc.x += v0 > 0.f ? v0 : 0.f;
            acc.y += v1 > 0.f ? v1 : 0.f;
        }

        #pragma unroll
        for (int j = 0; j < GRP; ++j) {
            ma[j] = mb[j]; mb[j] = mc[j]; mc[j] = mnn[j];
            xcur[j] = xn1[j]; xn1[j] = xn2[j];
        }
    }
    flush_row(agg, cur, d, acc, first, last);
}

// ---------------------------------------------------------------------------
// Stage 2: MFMA MLP (R5-exact).  x_res = relu(h@W1+b1)@W2+b2.
// ---------------------------------------------------------------------------
#define MROWS 64
#define HSTR  132
__global__ __launch_bounds__(256) void mlp_mfma_kernel(
    const float* __restrict__ x, const float* __restrict__ agg,
    const float* __restrict__ epsp,
    const short* __restrict__ wb1t, const float* __restrict__ b1,
    const short* __restrict__ wb2t, const float* __restrict__ b2,
    float* __restrict__ xres, int N)
{
    __shared__ float hsh[MROWS * HSTR];   // 33.8 KB
    const int row0 = blockIdx.x * MROWS;
    const float ep = 1.0f + epsp[0];

    for (int i = threadIdx.x; i < MROWS * D / 4; i += 256) {
        const int flat = i * 4;
        const int r = flat >> 7;
        const int c = flat & (D - 1);
        const int row = row0 + r;
        float4 hv = make_float4(0.f, 0.f, 0.f, 0.f);
        if (row < N) {
            const float4 xv = *(const float4*)(x   + (size_t)row * D + c);
            const float4 av = *(const float4*)(agg + (size_t)row * D + c);
            hv = make_float4(ep * xv.x + av.x, ep * xv.y + av.y,
                             ep * xv.z + av.z, ep * xv.w + av.w);
        }
        *(float4*)(hsh + r * HSTR + c) = hv;
    }
    __syncthreads();

    const int lane = threadIdx.x & 63;
    const int wrow = (threadIdx.x >> 6) * 16;  // wave's 16-row window
    const int m = lane & 15;
    const int q = lane >> 4;

    f32x4 acc[8];

    // ---- layer 1 ----
    #pragma unroll
    for (int ct = 0; ct < 8; ++ct) {
        const float b = b1[ct * 16 + m];
        acc[ct] = (f32x4){b, b, b, b};
    }
    #pragma unroll
    for (int ks = 0; ks < 4; ++ks) {
        const float* ap = hsh + (wrow + m) * HSTR + ks * 32 + q * 8;
        float av[8];
        *(float4*)(av)     = *(const float4*)ap;
        *(float4*)(av + 4) = *(const float4*)(ap + 4);
        bf16x8 a;
        #pragma unroll
        for (int j = 0; j < 8; ++j) a[j] = f2bf(av[j]);
        #pragma unroll
        for (int ct = 0; ct < 8; ++ct) {
            const bf16x8 b = *(const bf16x8*)(wb1t + (ct * 16 + m) * D + ks * 32 + q * 8);
            acc[ct] = __builtin_amdgcn_mfma_f32_16x16x32_bf16(a, b, acc[ct], 0, 0, 0);
        }
    }
    #pragma unroll
    for (int ct = 0; ct < 8; ++ct)
        #pragma unroll
        for (int r = 0; r < 4; ++r) {
            const float v = acc[ct][r];
            hsh[(wrow + q * 4 + r) * HSTR + ct * 16 + m] = v > 0.f ? v : 0.f;
        }

    // ---- layer 2 ----
    #pragma unroll
    for (int ct = 0; ct < 8; ++ct) {
        const float b = b2[ct * 16 + m];
        acc[ct] = (f32x4){b, b, b, b};
    }
    #pragma unroll
    for (int ks = 0; ks < 4; ++ks) {
        const float* ap = hsh + (wrow + m) * HSTR + ks * 32 + q * 8;
        float av[8];
        *(float4*)(av)     = *(const float4*)ap;
        *(float4*)(av + 4) = *(const float4*)(ap + 4);
        bf16x8 a;
        #pragma unroll
        for (int j = 0; j < 8; ++j) a[j] = f2bf(av[j]);
        #pragma unroll
        for (int ct = 0; ct < 8; ++ct) {
            const bf16x8 b = *(const bf16x8*)(wb2t + (ct * 16 + m) * D + ks * 32 + q * 8);
            acc[ct] = __builtin_amdgcn_mfma_f32_16x16x32_bf16(a, b, acc[ct], 0, 0, 0);
        }
    }
    #pragma unroll
    for (int r = 0; r < 4; ++r) {
        const int row = row0 + wrow + q * 4 + r;
        if (row < N) {
            #pragma unroll
            for (int ct = 0; ct < 8; ++ct)
                xres[(size_t)row * D + ct * 16 + m] = acc[ct][r];
        }
    }
}

// ---------------------------------------------------------------------------
// Stage 3: per-(graph,pocket) masked sums (R5-exact)
// ---------------------------------------------------------------------------
#define PPARTS 32
__global__ __launch_bounds__(128) void pocket_sum_kernel(
    const float* __restrict__ xres, const float* __restrict__ pmask,
    const int* __restrict__ batch,
    float* __restrict__ psum, float* __restrict__ pcnt, int N)
{
    const int g = blockIdx.x / PPARTS;
    const int part = blockIdx.x % PPARTS;

    int lo, hi;
    {
        int l = 0, r = N;
        while (l < r) { int m = (l + r) >> 1; if (batch[m] < g) l = m + 1; else r = m; }
        lo = l;
        r = N;
        while (l < r) { int m = (l + r) >> 1; if (batch[m] < g + 1) l = m + 1; else r = m; }
        hi = l;
    }
    const int cnt = hi - lo;
    const int per = (cnt + PPARTS - 1) / PPARTS;
    const int s = lo + part * per;
    const int e = min(s + per, hi);

    const int d = threadIdx.x;
    float acc[K];
    #pragma unroll
    for (int k = 0; k < K; ++k) acc[k] = 0.0f;
    float c = 0.0f;

    for (int n = s; n < e; ++n) {
        const float xv = xres[(size_t)n * D + d];
        const float4 m0 = *(const float4*)(pmask + (size_t)n * K);
        const float4 m1 = *(const float4*)(pmask + (size_t)n * K + 4);
        acc[0] += m0.x * xv; acc[1] += m0.y * xv;
        acc[2] += m0.z * xv; acc[3] += m0.w * xv;
        acc[4] += m1.x * xv; acc[5] += m1.y * xv;
        acc[6] += m1.z * xv; acc[7] += m1.w * xv;
        if (d < K) c += pmask[(size_t)n * K + d];
    }
    #pragma unroll
    for (int k = 0; k < K; ++k)
        atomicAdd(&psum[(size_t)g * (K * D) + k * D + d], acc[k]);
    if (d < K) atomicAdd(&pcnt[g * K + d], c);
}

// ---------------------------------------------------------------------------
// Stage 4: pocket_emb = (psum / (pcnt + 1e-9)) @ Wv + bv
// ---------------------------------------------------------------------------
__global__ __launch_bounds__(128) void pocket_emb_kernel(
    const float* __restrict__ psum, const float* __restrict__ pcnt,
    const float* __restrict__ Wv, const float* __restrict__ bv,
    float* __restrict__ pemb)
{
    __shared__ float smean[K * D];
    __shared__ float scnt[K];
    const int g = blockIdx.x;
    const int d = threadIdx.x;
    if (d < K) scnt[d] = pcnt[g * K + d];
    __syncthreads();
    #pragma unroll
    for (int k = 0; k < K; ++k)
        smean[k * D + d] = psum[(size_t)g * (K * D) + k * D + d] / (scnt[k] + 1e-9f);
    __syncthreads();

    float acc[K];
    const float bvv = bv[d];
    #pragma unroll
    for (int k = 0; k < K; ++k) acc[k] = bvv;
    for (int j = 0; j < D; ++j) {
        const float w = Wv[j * D + d];
        #pragma unroll
        for (int k = 0; k < K; ++k) acc[k] += smean[k * D + j] * w;
    }
    #pragma unroll
    for (int k = 0; k < K; ++k)
        pemb[(size_t)g * (K * D) + k * D + d] = acc[k];
}

// ---------------------------------------------------------------------------
// Stage 5: feedback gather + LayerNorm + ReLU. One wave per node.
// ---------------------------------------------------------------------------
__global__ __launch_bounds__(256) void ln_kernel(
    const float* __restrict__ xres, const float* __restrict__ pmask,
    const int* __restrict__ batch, const float* __restrict__ pemb,
    const float* __restrict__ gamma, const float* __restrict__ beta,
    float* __restrict__ out, int N)
{
    const int wave = threadIdx.x >> 6;
    const int lane = threadIdx.x & 63;
    const int n = blockIdx.x * 4 + wave;
    if (n >= N) return;
    const int d = lane * 2;

    float2 v = *(const float2*)(xres + (size_t)n * D + d);
    const int g = batch[n];
    const float* pe = pemb + (size_t)g * (K * D);
    const float4 m0 = *(const float4*)(pmask + (size_t)n * K);
    const float4 m1 = *(const float4*)(pmask + (size_t)n * K + 4);
    const float mk[K] = {m0.x, m0.y, m0.z, m0.w, m1.x, m1.y, m1.z, m1.w};
    #pragma unroll
    for (int k = 0; k < K; ++k) {
        if (mk[k] != 0.0f) {   // wave-uniform branch
            const float2 p = *(const float2*)(pe + k * D + d);
            v.x += mk[k] * p.x;
            v.y += mk[k] * p.y;
        }
    }

    float s = v.x + v.y;
    #pragma unroll
    for (int off = 32; off; off >>= 1) s += __shfl_xor(s, off, 64);
    const float mu = s * (1.0f / 128.0f);
    const float d0 = v.x - mu, d1 = v.y - mu;
    float sq = d0 * d0 + d1 * d1;
    #pragma unroll
    for (int off = 32; off; off >>= 1) sq += __shfl_xor(sq, off, 64);
    const float var = sq * (1.0f / 128.0f);
    const float inv = rsqrtf(var + 1e-5f);

    const float2 gm = *(const float2*)(gamma + d);
    const float2 bt = *(const float2*)(beta + d);
    float y0 = d0 * inv * gm.x + bt.x;
    float y1 = d1 * inv * gm.y + bt.y;
    y0 = y0 > 0.0f ? y0 : 0.0f;
    y1 = y1 > 0.0f ? y1 : 0.0f;
    *(float2*)(out + (size_t)n * D + d) = make_float2(y0, y1);
}

// ---------------------------------------------------------------------------
extern "C" void kernel_launch(void* const* d_in, const int* in_sizes, int n_in,
                              void* d_out, int out_size, void* d_ws, size_t ws_size,
                              hipStream_t stream)
{
    const float* x     = (const float*)d_in[0];
    const int*   ei    = (const int*)  d_in[1];
    const float* ea    = (const float*)d_in[2];
    const float* pmask = (const float*)d_in[3];
    const int*   batch = (const int*)  d_in[4];
    const float* We    = (const float*)d_in[5];
    const float* be    = (const float*)d_in[6];
    const float* W1    = (const float*)d_in[7];
    const float* b1    = (const float*)d_in[8];
    const float* W2    = (const float*)d_in[9];
    const float* b2    = (const float*)d_in[10];
    const float* epsp  = (const float*)d_in[11];
    const float* gamma = (const float*)d_in[12];
    const float* beta  = (const float*)d_in[13];
    const float* Wv    = (const float*)d_in[14];
    const float* bv    = (const float*)d_in[15];
    float* out = (float*)d_out;

    const int N = in_sizes[0] / D;     // 50000
    const int E = in_sizes[1] / 2;     // 600000
    const int* src = ei;
    const int* dst = ei + E;

    // Workspace: [deg | agg | psum | pcnt] (single memset), xres (aliased
    // below), pemb, scan scratch, xb (bf16 x), wb1t/wb2t/webt.  (R5 layout.)
    int*   deg  = (int*)d_ws;                           // N
    float* agg  = (float*)(deg + N);                    // N*D
    float* psum = agg + (size_t)N * D;                  // B*K*D
    float* pcnt = psum + (size_t)BGRAPH * K * D;        // B*K
    float* xres = pcnt + (size_t)BGRAPH * K;            // N*D
    float* pemb = xres + (size_t)N * D;                 // B*K*D
    float* extra = pemb + (size_t)BGRAPH * K * D;       // scan scratch (128)
    __hip_bfloat16* xb = (__hip_bfloat16*)(extra + 128);// N*D bf16
    short* wb1t = (short*)(xb + (size_t)N * D);         // D*D bf16
    short* wb2t = wb1t + (size_t)D * D;                 // D*D bf16
    short* webt = wb2t + (size_t)D * D;                 // 2*128*32 bf16 (8K shorts)

    // Aliased inside xres region (cursor 0.2MB + md 4.8MB + eabs 19.2MB
    // = 24.2MB < 25.6MB); all consumed before mlp writes xres.
    int*   cursor = (int*)xres;                         // N
    uint2* md  = (uint2*)(((uintptr_t)(cursor + N) + 15) & ~(uintptr_t)15); // E
    short* eabs = (short*)(md + E);                     // E*16 bf16, sorted order

    int*  bsum  = (int*)extra;                          // 64

    const int nb = (N + 1023) / 1024;                   // scan blocks (49)
    const int nchunks = (E + CH - 1) / CH;              // 9375
    const int NX = N * D;
    const int NBX = NX / 2048;                          // 3125 (exact)
    const int NBW = (2 * D * D + 2 * 128 * 32) / 256;   // 160 (exact)
    const int NBH = (E / 4 + 255) / 256;                // 586

    const size_t zero_bytes =
        ((size_t)N + (size_t)N * D + (size_t)BGRAPH * K * D + BGRAPH * K) * sizeof(float);
    hipMemsetAsync(d_ws, 0, zero_bytes, stream);

    prep_kernel<<<NBX + NBW + NBH, 256, 0, stream>>>(
        x, W1, W2, We, be, dst, xb, wb1t, wb2t, webt, deg,
        NX, E, NBX, NBW);
    scan_partial_kernel<<<nb, 256, 0, stream>>>(deg, bsum, N);
    scan_final_kernel<<<nb, 256, 0, stream>>>(deg, bsum, cursor, N, nb);
    scatter_kernel<<<(E + 255) / 256, 256, 0, stream>>>(
        src, dst, ea, cursor, md, eabs, E);
    gine_reduce_kernel<<<(nchunks + 3) / 4, 256, 0, stream>>>(
        xb, md, eabs, webt, agg, E);

    mlp_mfma_kernel<<<(N + MROWS - 1) / MROWS, 256, 0, stream>>>(
        x, agg, epsp, wb1t, b1, wb2t, b2, xres, N);
    pocket_sum_kernel<<<BGRAPH * PPARTS, 128, 0, stream>>>(
        xres, pmask, batch, psum, pcnt, N);
    pocket_emb_kernel<<<BGRAPH, 128, 0, stream>>>(psum, pcnt, Wv, bv, pemb);
    ln_kernel<<<(N + 3) / 4, 256, 0, stream>>>(
        xres, pmask, batch, pemb, gamma, beta, out, N);
}

// Round 12
// 345.427 us; speedup vs baseline: 1.0290x; 1.0290x over previous
//
#include <hip/hip_runtime.h>
#include <hip/hip_bf16.h>
#include <stdint.h>

#define D 128
#define K 8
#define BGRAPH 64
#define CH 64    // edges per wave in gine_reduce
#define GRP 4    // edges per inner group

typedef __attribute__((ext_vector_type(8))) short bf16x8;
typedef __attribute__((ext_vector_type(4))) float f32x4;
typedef __attribute__((ext_vector_type(2))) float f32x2;

__device__ __forceinline__ short f2bf(float f) {
    union { float f; uint32_t u; } v; v.f = f;
    const uint32_t r = (v.u + 0x7fffu + ((v.u >> 16) & 1u)) >> 16;
    return (short)r;
}
__device__ __forceinline__ float bflo(uint32_t u) {
    union { uint32_t u; float f; } v; v.u = u << 16; return v.f;
}
__device__ __forceinline__ float bfhi(uint32_t u) {
    union { uint32_t u; float f; } v; v.u = u & 0xffff0000u; return v.f;
}

// ---------------------------------------------------------------------------
// Stage 0 (fused prep): cast x->bf16, W1/W2->bf16 transposed, We^T hi/lo bf16
// (K padded to 32, bias row at k=16), dst in-degree hist.
// ---------------------------------------------------------------------------
__global__ __launch_bounds__(256) void prep_kernel(
    const float* __restrict__ x,
    const float* __restrict__ W1, const float* __restrict__ W2,
    const float* __restrict__ We, const float* __restrict__ be,
    const int* __restrict__ dst,
    __hip_bfloat16* __restrict__ xb,
    short* __restrict__ wb1t, short* __restrict__ wb2t,
    short* __restrict__ webt,
    int* __restrict__ deg,
    int NX, int E, int NBX, int NBW)
{
    const int b = blockIdx.x;
    const int t = threadIdx.x;
    if (b < NBX) {
        // ---- cast x (8 floats/thread) ----
        const int i = b * 2048 + t * 8;
        if (i + 8 <= NX) {
            const float4 a = *(const float4*)(x + i);
            const float4 c = *(const float4*)(x + i + 4);
            short v[8];
            v[0] = f2bf(a.x); v[1] = f2bf(a.y); v[2] = f2bf(a.z); v[3] = f2bf(a.w);
            v[4] = f2bf(c.x); v[5] = f2bf(c.y); v[6] = f2bf(c.z); v[7] = f2bf(c.w);
            *(uint4*)((short*)xb + i) = *(const uint4*)v;
        }
    } else if (b < NBX + NBW) {
        const int idx = (b - NBX) * 256 + t;
        if (idx < 2 * D * D) {
            // ---- W1/W2 transpose cast (1 elem/thread) ----
            const int which = idx >> 14;           // 0: W1, 1: W2
            const int rem = idx & 16383;
            const int n = rem >> 7;
            const int k = rem & 127;
            const float* W = which ? W2 : W1;
            short* O = which ? wb2t : wb1t;
            O[n * D + k] = f2bf(W[(size_t)k * D + n]);
        } else {
            // ---- webt[2][128][32]: We^T hi/lo bf16, bias row at k=16 ----
            const int widx = idx - 2 * D * D;      // 0..8191
            const int h = widx >> 12;              // 0 hi, 1 lo
            const int c = (widx >> 5) & 127;
            const int k = widx & 31;
            float val = 0.f;
            if (k < 16) val = We[k * D + c];
            else if (k == 16) val = be[c];
            const short hi = f2bf(val);
            short outv;
            if (h == 0) outv = hi;
            else {
                union { uint32_t u; float f; } fh;
                fh.u = ((uint32_t)(unsigned short)hi) << 16;
                outv = f2bf(val - fh.f);
            }
            webt[(h << 12) + c * 32 + k] = outv;
        }
    } else {
        // ---- dst histogram (4 edges/thread) ----
        const int i = ((b - NBX - NBW) * 256 + t) * 4;
        if (i + 4 <= E) {
            const int4 v = *(const int4*)(dst + i);
            atomicAdd(&deg[v.x], 1);
            atomicAdd(&deg[v.y], 1);
            atomicAdd(&deg[v.z], 1);
            atomicAdd(&deg[v.w], 1);
        } else {
            for (int j = i; j < E; ++j) atomicAdd(&deg[dst[j]], 1);
        }
    }
}

// ---------------------------------------------------------------------------
// Stage 1b: two-phase exclusive scan of deg[N] -> cursor[N].
// scan_final folds in the old scan_top: every block redundantly scans the
// 49-entry bsum array in LDS (parallel across blocks; -1 dispatch).
// ---------------------------------------------------------------------------
__global__ __launch_bounds__(256) void scan_partial_kernel(
    const int* __restrict__ deg, int* __restrict__ bsum, int N)
{
    const int t = threadIdx.x;
    const int base = (blockIdx.x * 256 + t) * 4;
    int s = 0;
    if (base + 4 <= N) {
        const int4 v = *(const int4*)(deg + base);
        s = v.x + v.y + v.z + v.w;
    } else {
        for (int j = base; j < N; ++j) s += deg[j];
    }
    __shared__ int red[256];
    red[t] = s;
    __syncthreads();
    for (int off = 128; off; off >>= 1) {
        if (t < off) red[t] += red[t + off];
        __syncthreads();
    }
    if (t == 0) bsum[blockIdx.x] = red[0];
}

__global__ __launch_bounds__(256) void scan_final_kernel(
    const int* __restrict__ deg, const int* __restrict__ bsum,
    int* __restrict__ cursor, int N, int nb)
{
    __shared__ int topsh[64];
    __shared__ int sh[256];
    const int t = threadIdx.x;

    // ---- inline top-scan of bsum[nb] (nb <= 64) ----
    const int own = bsum[blockIdx.x];
    if (t < 64) topsh[t] = (t < nb) ? bsum[t] : 0;
    __syncthreads();
    for (int off = 1; off < 64; off <<= 1) {
        int u = 0;
        if (t < 64 && t >= off) u = topsh[t - off];
        __syncthreads();
        if (t < 64) topsh[t] += u;
        __syncthreads();
    }
    const int extop = topsh[blockIdx.x] - own;     // exclusive top offset

    const int base = (blockIdx.x * 256 + t) * 4;
    int v0 = 0, v1 = 0, v2 = 0, v3 = 0;
    if (base + 4 <= N) {
        const int4 v = *(const int4*)(deg + base);
        v0 = v.x; v1 = v.y; v2 = v.z; v3 = v.w;
    } else {
        if (base     < N) v0 = deg[base];
        if (base + 1 < N) v1 = deg[base + 1];
        if (base + 2 < N) v2 = deg[base + 2];
        if (base + 3 < N) v3 = deg[base + 3];
    }
    const int s = v0 + v1 + v2 + v3;
    sh[t] = s;
    __syncthreads();
    for (int off = 1; off < 256; off <<= 1) {
        const int u = (t >= off) ? sh[t - off] : 0;
        __syncthreads();
        sh[t] += u;
        __syncthreads();
    }
    int ex = extop + sh[t] - s;
    if (base < N)     { cursor[base]     = ex; } ex += v0;
    if (base + 1 < N) { cursor[base + 1] = ex; } ex += v1;
    if (base + 2 < N) { cursor[base + 2] = ex; } ex += v2;
    if (base + 3 < N) { cursor[base + 3] = ex; }
}

// ---------------------------------------------------------------------------
// Stage 1c: fused scatter (R5 form): packed (src|dst<<16, eid) into dst-
// grouped order AND bf16 ea row materialized at sorted position (coalesced
// ea read, scattered 32B write).
// ---------------------------------------------------------------------------
__global__ __launch_bounds__(256) void scatter_kernel(
    const int* __restrict__ src, const int* __restrict__ dst,
    const float* __restrict__ ea,
    int* __restrict__ cursor, uint2* __restrict__ md,
    short* __restrict__ eabs, int E)
{
    const int i = blockIdx.x * 256 + threadIdx.x;
    if (i < E) {
        const unsigned sv = (unsigned)src[i];
        const unsigned dv = (unsigned)dst[i];
        const int p = atomicAdd(&cursor[dv], 1);
        md[p] = make_uint2(sv | (dv << 16), (unsigned)i);
        const float4* ep = (const float4*)(ea + (size_t)i * 16);
        const float4 a = ep[0], b = ep[1], c = ep[2], e4 = ep[3];
        short v[16];
        v[0]  = f2bf(a.x);  v[1]  = f2bf(a.y);  v[2]  = f2bf(a.z);  v[3]  = f2bf(a.w);
        v[4]  = f2bf(b.x);  v[5]  = f2bf(b.y);  v[6]  = f2bf(b.z);  v[7]  = f2bf(b.w);
        v[8]  = f2bf(c.x);  v[9]  = f2bf(c.y);  v[10] = f2bf(c.z);  v[11] = f2bf(c.w);
        v[12] = f2bf(e4.x); v[13] = f2bf(e4.y); v[14] = f2bf(e4.z); v[15] = f2bf(e4.w);
        uint4* op = (uint4*)(eabs + (size_t)p * 16);
        op[0] = *(const uint4*)v;
        op[1] = *(const uint4*)(v + 8);
    }
}

// ---------------------------------------------------------------------------
// Stage 1d: edge-parallel gather-reduce. R10-exact (best measured): 16x132
// linear LDS tile (33.8KB, 4 blocks/CU), md 3-deep, x 2-deep. ea@We+be on
// the MFMA pipe; serial dst-segmented consume from LDS.
// ---------------------------------------------------------------------------
__device__ __forceinline__ void flush_row(
    float* __restrict__ agg, int node, int d, f32x2 acc, int first, int last)
{
    float* p = agg + (size_t)node * D + d;
    if (node == first || node == last) {
        if (acc.x != 0.f) atomicAdd(p,     acc.x);
        if (acc.y != 0.f) atomicAdd(p + 1, acc.y);
    } else {
        *(f32x2*)p = acc;
    }
}

__global__ __launch_bounds__(256) void gine_reduce_kernel(
    const __hip_bfloat16* __restrict__ xb, const uint2* __restrict__ md,
    const short* __restrict__ eabs, const short* __restrict__ webt,
    float* __restrict__ agg, int E)
{
    __shared__ float lsh[4][16 * 132];   // 33.8 KB, wave-private tiles
    const int wave = threadIdx.x >> 6;
    const int lane = threadIdx.x & 63;
    const int chunk = __builtin_amdgcn_readfirstlane(blockIdx.x * 4 + wave);
    const int e0 = chunk * CH;
    if (e0 >= E) return;
    const int d = lane * 2;
    const int m = lane & 15;
    const int q = lane >> 4;
    float* myl = lsh[wave];
    const int NG = CH / GRP;                       // 16

    // B fragments: col = ct*16+m, k = q*8..q*8+7 (hi and lo tables)
    bf16x8 bH[8], bL[8];
    #pragma unroll
    for (int ct = 0; ct < 8; ++ct) {
        bH[ct] = *(const bf16x8*)(webt +        (ct * 16 + m) * 32 + q * 8);
        bL[ct] = *(const bf16x8*)(webt + 4096 + (ct * 16 + m) * 32 + q * 8);
    }

    // A fragment for mgroup 0: STREAMING read at sorted position e0+m.
    uint4 afcur = *(const uint4*)(eabs + (size_t)(e0 + m) * 16 + (q & 1) * 8);

    // scalar md pipeline + x prefetch (GRP granularity)
    uint2 ma[GRP], mb[GRP], mc[GRP];
    #pragma unroll
    for (int j = 0; j < GRP; ++j) ma[j] = md[e0 + j];
    #pragma unroll
    for (int j = 0; j < GRP; ++j) mb[j] = md[e0 + GRP + j];
    #pragma unroll
    for (int j = 0; j < GRP; ++j) mc[j] = md[e0 + 2 * GRP + j];

    uint32_t xcur[GRP], xn1[GRP];
    #pragma unroll
    for (int j = 0; j < GRP; ++j)
        xcur[j] = *(const uint32_t*)(xb + (size_t)(ma[j].x & 0xffffu) * D + d);
    #pragma unroll
    for (int j = 0; j < GRP; ++j)
        xn1[j] = *(const uint32_t*)(xb + (size_t)(mb[j].x & 0xffffu) * D + d);

    const int first = (int)(ma[0].x >> 16);
    const int last  = (int)(md[e0 + CH - 1].x >> 16);

    f32x2 acc = {0.f, 0.f};
    int cur = first;

    for (int g = 0; g < NG; ++g) {
        if ((g & 3) == 0) {
            // ---- MFMA block for mgroup mg; streaming prefetch A for mg+1 ----
            const int mg = g >> 2;
            uint4 afn = make_uint4(0u, 0u, 0u, 0u);
            if (mg < 3)
                afn = *(const uint4*)(eabs +
                    (size_t)(e0 + (mg + 1) * 16 + m) * 16 + (q & 1) * 8);
            uint4 au = afcur;
            if (q >= 2)
                au = make_uint4(q == 2 ? 0x3f80u : 0u, 0u, 0u, 0u); // k16 = 1.0
            const bf16x8 a = *(const bf16x8*)&au;
            f32x4 mm[8];
            #pragma unroll
            for (int ct = 0; ct < 8; ++ct) {
                const f32x4 z = {0.f, 0.f, 0.f, 0.f};
                mm[ct] = __builtin_amdgcn_mfma_f32_16x16x32_bf16(a, bL[ct], z, 0, 0, 0);
            }
            #pragma unroll
            for (int ct = 0; ct < 8; ++ct)
                mm[ct] = __builtin_amdgcn_mfma_f32_16x16x32_bf16(a, bH[ct], mm[ct], 0, 0, 0);
            // C: edge row = q*4+r, col = ct*16+m  (stride 132: conflict-free)
            #pragma unroll
            for (int ct = 0; ct < 8; ++ct)
                #pragma unroll
                for (int r = 0; r < 4; ++r)
                    myl[(q * 4 + r) * 132 + ct * 16 + m] = mm[ct][r];
            afcur = afn;
        }

        // prefetch: meta g+3, x g+2
        uint2 mnn[GRP] = {};
        uint32_t xn2[GRP] = {};
        if (g + 3 < NG) {
            #pragma unroll
            for (int j = 0; j < GRP; ++j) mnn[j] = md[e0 + (g + 3) * GRP + j];
        }
        if (g + 2 < NG) {
            #pragma unroll
            for (int j = 0; j < GRP; ++j)
                xn2[j] = *(const uint32_t*)(xb + (size_t)(mc[j].x & 0xffffu) * D + d);
        }

        #pragma unroll
        for (int j = 0; j < GRP; ++j) {
            const int dk = (int)(ma[j].x >> 16);
            if (dk != cur) {                  // wave-uniform scalar branch
                flush_row(agg, cur, d, acc, first, last);
                acc.x = 0.f; acc.y = 0.f;
                cur = dk;
            }
            const uint32_t xu = xcur[j];
            const float2 em = *(const float2*)(myl + ((g & 3) * GRP + j) * 132 + d);
            const float v0 = em.x + bflo(xu);
            const float v1 = em.y + bfhi(xu);
            acc.x += v0 > 0.f ? v0 : 0.f;
            acc.y += v1 > 0.f ? v1 : 0.f;
        }

        #pragma unroll
        for (int j = 0; j < GRP; ++j) {
            ma[j] = mb[j]; mb[j] = mc[j]; mc[j] = mnn[j];
            xcur[j] = xn1[j]; xn1[j] = xn2[j];
        }
    }
    flush_row(agg, cur, d, acc, first, last);
}

// ---------------------------------------------------------------------------
// Stage 2: MFMA MLP (R5-exact).  x_res = relu(h@W1+b1)@W2+b2.
// ---------------------------------------------------------------------------
#define MROWS 64
#define HSTR  132
__global__ __launch_bounds__(256) void mlp_mfma_kernel(
    const float* __restrict__ x, const float* __restrict__ agg,
    const float* __restrict__ epsp,
    const short* __restrict__ wb1t, const float* __restrict__ b1,
    const short* __restrict__ wb2t, const float* __restrict__ b2,
    float* __restrict__ xres, int N)
{
    __shared__ float hsh[MROWS * HSTR];   // 33.8 KB
    const int row0 = blockIdx.x * MROWS;
    const float ep = 1.0f + epsp[0];

    for (int i = threadIdx.x; i < MROWS * D / 4; i += 256) {
        const int flat = i * 4;
        const int r = flat >> 7;
        const int c = flat & (D - 1);
        const int row = row0 + r;
        float4 hv = make_float4(0.f, 0.f, 0.f, 0.f);
        if (row < N) {
            const float4 xv = *(const float4*)(x   + (size_t)row * D + c);
            const float4 av = *(const float4*)(agg + (size_t)row * D + c);
            hv = make_float4(ep * xv.x + av.x, ep * xv.y + av.y,
                             ep * xv.z + av.z, ep * xv.w + av.w);
        }
        *(float4*)(hsh + r * HSTR + c) = hv;
    }
    __syncthreads();

    const int lane = threadIdx.x & 63;
    const int wrow = (threadIdx.x >> 6) * 16;  // wave's 16-row window
    const int m = lane & 15;
    const int q = lane >> 4;

    f32x4 acc[8];

    // ---- layer 1 ----
    #pragma unroll
    for (int ct = 0; ct < 8; ++ct) {
        const float b = b1[ct * 16 + m];
        acc[ct] = (f32x4){b, b, b, b};
    }
    #pragma unroll
    for (int ks = 0; ks < 4; ++ks) {
        const float* ap = hsh + (wrow + m) * HSTR + ks * 32 + q * 8;
        float av[8];
        *(float4*)(av)     = *(const float4*)ap;
        *(float4*)(av + 4) = *(const float4*)(ap + 4);
        bf16x8 a;
        #pragma unroll
        for (int j = 0; j < 8; ++j) a[j] = f2bf(av[j]);
        #pragma unroll
        for (int ct = 0; ct < 8; ++ct) {
            const bf16x8 b = *(const bf16x8*)(wb1t + (ct * 16 + m) * D + ks * 32 + q * 8);
            acc[ct] = __builtin_amdgcn_mfma_f32_16x16x32_bf16(a, b, acc[ct], 0, 0, 0);
        }
    }
    #pragma unroll
    for (int ct = 0; ct < 8; ++ct)
        #pragma unroll
        for (int r = 0; r < 4; ++r) {
            const float v = acc[ct][r];
            hsh[(wrow + q * 4 + r) * HSTR + ct * 16 + m] = v > 0.f ? v : 0.f;
        }

    // ---- layer 2 ----
    #pragma unroll
    for (int ct = 0; ct < 8; ++ct) {
        const float b = b2[ct * 16 + m];
        acc[ct] = (f32x4){b, b, b, b};
    }
    #pragma unroll
    for (int ks = 0; ks < 4; ++ks) {
        const float* ap = hsh + (wrow + m) * HSTR + ks * 32 + q * 8;
        float av[8];
        *(float4*)(av)     = *(const float4*)ap;
        *(float4*)(av + 4) = *(const float4*)(ap + 4);
        bf16x8 a;
        #pragma unroll
        for (int j = 0; j < 8; ++j) a[j] = f2bf(av[j]);
        #pragma unroll
        for (int ct = 0; ct < 8; ++ct) {
            const bf16x8 b = *(const bf16x8*)(wb2t + (ct * 16 + m) * D + ks * 32 + q * 8);
            acc[ct] = __builtin_amdgcn_mfma_f32_16x16x32_bf16(a, b, acc[ct], 0, 0, 0);
        }
    }
    #pragma unroll
    for (int r = 0; r < 4; ++r) {
        const int row = row0 + wrow + q * 4 + r;
        if (row < N) {
            #pragma unroll
            for (int ct = 0; ct < 8; ++ct)
                xres[(size_t)row * D + ct * 16 + m] = acc[ct][r];
        }
    }
}

// ---------------------------------------------------------------------------
// Stage 3: per-(graph,pocket) masked sums (R5-exact)
// ---------------------------------------------------------------------------
#define PPARTS 32
__global__ __launch_bounds__(128) void pocket_sum_kernel(
    const float* __restrict__ xres, const float* __restrict__ pmask,
    const int* __restrict__ batch,
    float* __restrict__ psum, float* __restrict__ pcnt, int N)
{
    const int g = blockIdx.x / PPARTS;
    const int part = blockIdx.x % PPARTS;

    int lo, hi;
    {
        int l = 0, r = N;
        while (l < r) { int m = (l + r) >> 1; if (batch[m] < g) l = m + 1; else r = m; }
        lo = l;
        r = N;
        while (l < r) { int m = (l + r) >> 1; if (batch[m] < g + 1) l = m + 1; else r = m; }
        hi = l;
    }
    const int cnt = hi - lo;
    const int per = (cnt + PPARTS - 1) / PPARTS;
    const int s = lo + part * per;
    const int e = min(s + per, hi);

    const int d = threadIdx.x;
    float acc[K];
    #pragma unroll
    for (int k = 0; k < K; ++k) acc[k] = 0.0f;
    float c = 0.0f;

    for (int n = s; n < e; ++n) {
        const float xv = xres[(size_t)n * D + d];
        const float4 m0 = *(const float4*)(pmask + (size_t)n * K);
        const float4 m1 = *(const float4*)(pmask + (size_t)n * K + 4);
        acc[0] += m0.x * xv; acc[1] += m0.y * xv;
        acc[2] += m0.z * xv; acc[3] += m0.w * xv;
        acc[4] += m1.x * xv; acc[5] += m1.y * xv;
        acc[6] += m1.z * xv; acc[7] += m1.w * xv;
        if (d < K) c += pmask[(size_t)n * K + d];
    }
    #pragma unroll
    for (int k = 0; k < K; ++k)
        atomicAdd(&psum[(size_t)g * (K * D) + k * D + d], acc[k]);
    if (d < K) atomicAdd(&pcnt[g * K + d], c);
}

// ---------------------------------------------------------------------------
// Stage 4: pocket_emb = (psum / (pcnt + 1e-9)) @ Wv + bv
// ---------------------------------------------------------------------------
__global__ __launch_bounds__(128) void pocket_emb_kernel(
    const float* __restrict__ psum, const float* __restrict__ pcnt,
    const float* __restrict__ Wv, const float* __restrict__ bv,
    float* __restrict__ pemb)
{
    __shared__ float smean[K * D];
    __shared__ float scnt[K];
    const int g = blockIdx.x;
    const int d = threadIdx.x;
    if (d < K) scnt[d] = pcnt[g * K + d];
    __syncthreads();
    #pragma unroll
    for (int k = 0; k < K; ++k)
        smean[k * D + d] = psum[(size_t)g * (K * D) + k * D + d] / (scnt[k] + 1e-9f);
    __syncthreads();

    float acc[K];
    const float bvv = bv[d];
    #pragma unroll
    for (int k = 0; k < K; ++k) acc[k] = bvv;
    for (int j = 0; j < D; ++j) {
        const float w = Wv[j * D + d];
        #pragma unroll
        for (int k = 0; k < K; ++k) acc[k] += smean[k * D + j] * w;
    }
    #pragma unroll
    for (int k = 0; k < K; ++k)
        pemb[(size_t)g * (K * D) + k * D + d] = acc[k];
}

// ---------------------------------------------------------------------------
// Stage 5: feedback gather + LayerNorm + ReLU. One wave per node.
// ---------------------------------------------------------------------------
__global__ __launch_bounds__(256) void ln_kernel(
    const float* __restrict__ xres, const float* __restrict__ pmask,
    const int* __restrict__ batch, const float* __restrict__ pemb,
    const float* __restrict__ gamma, const float* __restrict__ beta,
    float* __restrict__ out, int N)
{
    const int wave = threadIdx.x >> 6;
    const int lane = threadIdx.x & 63;
    const int n = blockIdx.x * 4 + wave;
    if (n >= N) return;
    const int d = lane * 2;

    float2 v = *(const float2*)(xres + (size_t)n * D + d);
    const int g = batch[n];
    const float* pe = pemb + (size_t)g * (K * D);
    const float4 m0 = *(const float4*)(pmask + (size_t)n * K);
    const float4 m1 = *(const float4*)(pmask + (size_t)n * K + 4);
    const float mk[K] = {m0.x, m0.y, m0.z, m0.w, m1.x, m1.y, m1.z, m1.w};
    #pragma unroll
    for (int k = 0; k < K; ++k) {
        if (mk[k] != 0.0f) {   // wave-uniform branch
            const float2 p = *(const float2*)(pe + k * D + d);
            v.x += mk[k] * p.x;
            v.y += mk[k] * p.y;
        }
    }

    float s = v.x + v.y;
    #pragma unroll
    for (int off = 32; off; off >>= 1) s += __shfl_xor(s, off, 64);
    const float mu = s * (1.0f / 128.0f);
    const float d0 = v.x - mu, d1 = v.y - mu;
    float sq = d0 * d0 + d1 * d1;
    #pragma unroll
    for (int off = 32; off; off >>= 1) sq += __shfl_xor(sq, off, 64);
    const float var = sq * (1.0f / 128.0f);
    const float inv = rsqrtf(var + 1e-5f);

    const float2 gm = *(const float2*)(gamma + d);
    const float2 bt = *(const float2*)(beta + d);
    float y0 = d0 * inv * gm.x + bt.x;
    float y1 = d1 * inv * gm.y + bt.y;
    y0 = y0 > 0.0f ? y0 : 0.0f;
    y1 = y1 > 0.0f ? y1 : 0.0f;
    *(float2*)(out + (size_t)n * D + d) = make_float2(y0, y1);
}

// ---------------------------------------------------------------------------
extern "C" void kernel_launch(void* const* d_in, const int* in_sizes, int n_in,
                              void* d_out, int out_size, void* d_ws, size_t ws_size,
                              hipStream_t stream)
{
    const float* x     = (const float*)d_in[0];
    const int*   ei    = (const int*)  d_in[1];
    const float* ea    = (const float*)d_in[2];
    const float* pmask = (const float*)d_in[3];
    const int*   batch = (const int*)  d_in[4];
    const float* We    = (const float*)d_in[5];
    const float* be    = (const float*)d_in[6];
    const float* W1    = (const float*)d_in[7];
    const float* b1    = (const float*)d_in[8];
    const float* W2    = (const float*)d_in[9];
    const float* b2    = (const float*)d_in[10];
    const float* epsp  = (const float*)d_in[11];
    const float* gamma = (const float*)d_in[12];
    const float* beta  = (const float*)d_in[13];
    const float* Wv    = (const float*)d_in[14];
    const float* bv    = (const float*)d_in[15];
    float* out = (float*)d_out;

    const int N = in_sizes[0] / D;     // 50000
    const int E = in_sizes[1] / 2;     // 600000
    const int* src = ei;
    const int* dst = ei + E;

    // Workspace: [deg | agg | psum | pcnt] (single memset), xres (aliased
    // below), pemb, scan scratch, xb (bf16 x), wb1t/wb2t/webt.  (R5 layout.)
    int*   deg  = (int*)d_ws;                           // N
    float* agg  = (float*)(deg + N);                    // N*D
    float* psum = agg + (size_t)N * D;                  // B*K*D
    float* pcnt = psum + (size_t)BGRAPH * K * D;        // B*K
    float* xres = pcnt + (size_t)BGRAPH * K;            // N*D
    float* pemb = xres + (size_t)N * D;                 // B*K*D
    float* extra = pemb + (size_t)BGRAPH * K * D;       // scan scratch (128)
    __hip_bfloat16* xb = (__hip_bfloat16*)(extra + 128);// N*D bf16
    short* wb1t = (short*)(xb + (size_t)N * D);         // D*D bf16
    short* wb2t = wb1t + (size_t)D * D;                 // D*D bf16
    short* webt = wb2t + (size_t)D * D;                 // 2*128*32 bf16 (8K shorts)

    // Aliased inside xres region (cursor 0.2MB + md 4.8MB + eabs 19.2MB
    // = 24.2MB < 25.6MB); all consumed before mlp writes xres.
    int*   cursor = (int*)xres;                         // N
    uint2* md  = (uint2*)(((uintptr_t)(cursor + N) + 15) & ~(uintptr_t)15); // E
    short* eabs = (short*)(md + E);                     // E*16 bf16, sorted order

    int*  bsum  = (int*)extra;                          // 64

    const int nb = (N + 1023) / 1024;                   // scan blocks (49)
    const int nchunks = (E + CH - 1) / CH;              // 9375
    const int NX = N * D;
    const int NBX = NX / 2048;                          // 3125 (exact)
    const int NBW = (2 * D * D + 2 * 128 * 32) / 256;   // 160 (exact)
    const int NBH = (E / 4 + 255) / 256;                // 586

    const size_t zero_bytes =
        ((size_t)N + (size_t)N * D + (size_t)BGRAPH * K * D + BGRAPH * K) * sizeof(float);
    hipMemsetAsync(d_ws, 0, zero_bytes, stream);

    prep_kernel<<<NBX + NBW + NBH, 256, 0, stream>>>(
        x, W1, W2, We, be, dst, xb, wb1t, wb2t, webt, deg,
        NX, E, NBX, NBW);
    scan_partial_kernel<<<nb, 256, 0, stream>>>(deg, bsum, N);
    scan_final_kernel<<<nb, 256, 0, stream>>>(deg, bsum, cursor, N, nb);
    scatter_kernel<<<(E + 255) / 256, 256, 0, stream>>>(
        src, dst, ea, cursor, md, eabs, E);
    gine_reduce_kernel<<<(nchunks + 3) / 4, 256, 0, stream>>>(
        xb, md, eabs, webt, agg, E);

    mlp_mfma_kernel<<<(N + MROWS - 1) / MROWS, 256, 0, stream>>>(
        x, agg, epsp, wb1t, b1, wb2t, b2, xres, N);
    pocket_sum_kernel<<<BGRAPH * PPARTS, 128, 0, stream>>>(
        xres, pmask, batch, psum, pcnt, N);
    pocket_emb_kernel<<<BGRAPH, 128, 0, stream>>>(psum, pcnt, Wv, bv, pemb);
    ln_kernel<<<(N + 3) / 4, 256, 0, stream>>>(
        xres, pmask, batch, pemb, gamma, beta, out, N);
}